// Round 1
// baseline (3967.614 us; speedup 1.0000x reference)
//
#include <hip/hip_runtime.h>

// WL2 graph-conv layer, MI355X.
// Plan: K1 = XWn = X @ W_neighbor + 0.5*b_neighbor (fp32, W in LDS, 8x4 reg tile)
//       K2 = edge gather+relu+atomic scatter into conv (float4 lanes, 32 thr/edge)
//       K3 = fused XW_local & XW_filter GEMM + epilogue relu(l + f*conv + b)
// ws layout: [conv: N*128 f32][XWn: N*128 f32]  (204.8 MB)

constexpr int DIM = 128;

__global__ __launch_bounds__(256, 2) void gemm_neighbor_k(
    const float* __restrict__ X, const float* __restrict__ W,
    const float* __restrict__ bn, float* __restrict__ XWn, int Nrows) {
  __shared__ float Ws[DIM * DIM];  // 64 KB: W[k][u]
  const int tid = threadIdx.x;
  for (int i = tid * 4; i < DIM * DIM; i += 1024)
    *(float4*)(Ws + i) = *(const float4*)(W + i);
  __syncthreads();
  const int tx = tid & 31;   // unit group: units 4*tx..4*tx+3
  const int ty = tid >> 5;   // row group: 8 rows each
  const long r0 = (long)blockIdx.x * 64 + (long)ty * 8;
  long rr[8];
#pragma unroll
  for (int r = 0; r < 8; ++r) {
    long t = r0 + r;
    rr[r] = t < Nrows ? t : (long)(Nrows - 1);  // clamp loads; stores guarded
  }
  float acc[8][4];
#pragma unroll
  for (int r = 0; r < 8; ++r)
    acc[r][0] = acc[r][1] = acc[r][2] = acc[r][3] = 0.f;

  for (int k = 0; k < DIM; k += 4) {
    float4 w0 = *(const float4*)(Ws + (k + 0) * DIM + tx * 4);
    float4 w1 = *(const float4*)(Ws + (k + 1) * DIM + tx * 4);
    float4 w2 = *(const float4*)(Ws + (k + 2) * DIM + tx * 4);
    float4 w3 = *(const float4*)(Ws + (k + 3) * DIM + tx * 4);
#pragma unroll
    for (int r = 0; r < 8; ++r) {
      float4 xv = *(const float4*)(X + rr[r] * DIM + k);
      acc[r][0] += xv.x * w0.x + xv.y * w1.x + xv.z * w2.x + xv.w * w3.x;
      acc[r][1] += xv.x * w0.y + xv.y * w1.y + xv.z * w2.y + xv.w * w3.y;
      acc[r][2] += xv.x * w0.z + xv.y * w1.z + xv.z * w2.z + xv.w * w3.z;
      acc[r][3] += xv.x * w0.w + xv.y * w1.w + xv.z * w2.w + xv.w * w3.w;
    }
  }
  const float4 bv = *(const float4*)(bn + tx * 4);
#pragma unroll
  for (int r = 0; r < 8; ++r) {
    if (r0 + r < Nrows) {
      float4 o;
      o.x = acc[r][0] + 0.5f * bv.x;  // fold b_neighbor/2 so a+b gets it once
      o.y = acc[r][1] + 0.5f * bv.y;
      o.z = acc[r][2] + 0.5f * bv.z;
      o.w = acc[r][3] + 0.5f * bv.w;
      *(float4*)(XWn + (r0 + r) * DIM + tx * 4) = o;
    }
  }
}

__global__ __launch_bounds__(256) void edge_scatter_k(
    const float* __restrict__ XWn, const int* __restrict__ ra,
    const int* __restrict__ rb, const int* __restrict__ br,
    float* __restrict__ conv, int E) {
  const int e = blockIdx.x * 8 + (threadIdx.x >> 5);  // 32 threads per edge
  if (e >= E) return;
  const int u = (threadIdx.x & 31) * 4;
  const long a = ra[e];
  const long b = rb[e];
  const long c = br[e];
  const float4 va = *(const float4*)(XWn + a * DIM + u);
  const float4 vb = *(const float4*)(XWn + b * DIM + u);
  float4 m;
  m.x = fmaxf(va.x + vb.x, 0.f);
  m.y = fmaxf(va.y + vb.y, 0.f);
  m.z = fmaxf(va.z + vb.z, 0.f);
  m.w = fmaxf(va.w + vb.w, 0.f);
  float* dst = conv + c * DIM + u;
  atomicAdd(dst + 0, m.x);
  atomicAdd(dst + 1, m.y);
  atomicAdd(dst + 2, m.z);
  atomicAdd(dst + 3, m.w);
}

__global__ __launch_bounds__(256, 2) void final_fused_k(
    const float* __restrict__ X, const float* __restrict__ Wl,
    const float* __restrict__ Wf, const float* __restrict__ bias,
    const float* __restrict__ conv, float* __restrict__ out, int Nrows) {
  // Block covers 64 rows x 64 units (blockIdx.y picks unit half) so that
  // Wl-half + Wf-half = 64 KB LDS -> 2 blocks/CU.
  __shared__ float Wls[DIM * 64];
  __shared__ float Wfs[DIM * 64];
  const int tid = threadIdx.x;
  const int uh = blockIdx.y * 64;
  for (int i = tid * 4; i < DIM * 64; i += 1024) {
    const int k = i >> 6, j = i & 63;
    *(float4*)(Wls + i) = *(const float4*)(Wl + k * DIM + uh + j);
    *(float4*)(Wfs + i) = *(const float4*)(Wf + k * DIM + uh + j);
  }
  __syncthreads();
  const int tx = tid & 15;  // 16 unit groups x4 = 64 units
  const int ty = tid >> 4;  // 16 row groups x4 = 64 rows
  const int u = tx * 4;
  const long r0 = (long)blockIdx.x * 64 + (long)ty * 4;
  long rr[4];
#pragma unroll
  for (int r = 0; r < 4; ++r) {
    long t = r0 + r;
    rr[r] = t < Nrows ? t : (long)(Nrows - 1);
  }
  float accl[4][4], accf[4][4];
#pragma unroll
  for (int r = 0; r < 4; ++r)
#pragma unroll
    for (int j = 0; j < 4; ++j) {
      accl[r][j] = 0.f;
      accf[r][j] = 0.f;
    }

  for (int k = 0; k < DIM; k += 4) {
    float4 l0 = *(const float4*)(Wls + (k + 0) * 64 + u);
    float4 l1 = *(const float4*)(Wls + (k + 1) * 64 + u);
    float4 l2 = *(const float4*)(Wls + (k + 2) * 64 + u);
    float4 l3 = *(const float4*)(Wls + (k + 3) * 64 + u);
    float4 f0 = *(const float4*)(Wfs + (k + 0) * 64 + u);
    float4 f1 = *(const float4*)(Wfs + (k + 1) * 64 + u);
    float4 f2 = *(const float4*)(Wfs + (k + 2) * 64 + u);
    float4 f3 = *(const float4*)(Wfs + (k + 3) * 64 + u);
#pragma unroll
    for (int r = 0; r < 4; ++r) {
      float4 xv = *(const float4*)(X + rr[r] * DIM + k);
      accl[r][0] += xv.x * l0.x + xv.y * l1.x + xv.z * l2.x + xv.w * l3.x;
      accl[r][1] += xv.x * l0.y + xv.y * l1.y + xv.z * l2.y + xv.w * l3.y;
      accl[r][2] += xv.x * l0.z + xv.y * l1.z + xv.z * l2.z + xv.w * l3.z;
      accl[r][3] += xv.x * l0.w + xv.y * l1.w + xv.z * l2.w + xv.w * l3.w;
      accf[r][0] += xv.x * f0.x + xv.y * f1.x + xv.z * f2.x + xv.w * f3.x;
      accf[r][1] += xv.x * f0.y + xv.y * f1.y + xv.z * f2.y + xv.w * f3.y;
      accf[r][2] += xv.x * f0.z + xv.y * f1.z + xv.z * f2.z + xv.w * f3.z;
      accf[r][3] += xv.x * f0.w + xv.y * f1.w + xv.z * f2.w + xv.w * f3.w;
    }
  }
  const int ug = uh + u;
  const float4 bv = *(const float4*)(bias + ug);
#pragma unroll
  for (int r = 0; r < 4; ++r) {
    if (r0 + r < Nrows) {
      const float4 cv = *(const float4*)(conv + (r0 + r) * DIM + ug);
      float4 o;
      o.x = fmaxf(accl[r][0] + accf[r][0] * cv.x + bv.x, 0.f);
      o.y = fmaxf(accl[r][1] + accf[r][1] * cv.y + bv.y, 0.f);
      o.z = fmaxf(accl[r][2] + accf[r][2] * cv.z + bv.z, 0.f);
      o.w = fmaxf(accl[r][3] + accf[r][3] * cv.w + bv.w, 0.f);
      *(float4*)(out + (r0 + r) * DIM + ug) = o;
    }
  }
}

extern "C" void kernel_launch(void* const* d_in, const int* in_sizes, int n_in,
                              void* d_out, int out_size, void* d_ws, size_t ws_size,
                              hipStream_t stream) {
  const float* X  = (const float*)d_in[0];
  const int* ra   = (const int*)d_in[1];
  const int* rb   = (const int*)d_in[2];
  const int* br   = (const int*)d_in[3];
  const float* Wl = (const float*)d_in[4];
  const float* Wf = (const float*)d_in[5];
  const float* Wn = (const float*)d_in[6];
  const float* b  = (const float*)d_in[7];
  const float* bn = (const float*)d_in[8];
  float* out = (float*)d_out;

  const int N = in_sizes[0] / DIM;  // 200000
  const int E = in_sizes[1];        // 2000000

  float* conv = (float*)d_ws;                    // N*128 f32
  float* XWn  = conv + (size_t)N * DIM;          // N*128 f32

  hipMemsetAsync(conv, 0, (size_t)N * DIM * sizeof(float), stream);

  const int rowBlocks = (N + 63) / 64;
  gemm_neighbor_k<<<rowBlocks, 256, 0, stream>>>(X, Wn, bn, XWn, N);
  edge_scatter_k<<<(E + 7) / 8, 256, 0, stream>>>(XWn, ra, rb, br, conv, E);
  final_fused_k<<<dim3(rowBlocks, 2), 256, 0, stream>>>(X, Wl, Wf, b, conv, out, N);
}

// Round 2
// 1843.861 us; speedup vs baseline: 2.1518x; 2.1518x over previous
//
#include <hip/hip_runtime.h>

// WL2 graph-conv layer, MI355X — round 2: CSR-gather instead of fp32 scatter atomics.
// K0  memset counts
// K1  hist_k:   counts[br[e]]++                     (2M int atomics)
// K2  scan_k:   exclusive scan (single block)       -> offsets
// K3  fill_k:   edge_list[atomicAdd(offsets[r])]=e  (post-fill: offsets[r] = end of row r)
// K4  gemm_neighbor_k: XWn = X @ Wn + 0.5*bn        (fp32, W in LDS, 8x4 reg tile)
// K5  final_fused_k: per 64-row x 64-unit block: gather conv from CSR (registers),
//     then Wl/Wf GEMM, epilogue relu(l + f*conv + b). conv never materialized.
// ws: [XWn: N*128 f32][offsets: (N+1) i32][edge_list: E i32]  ~= 112 MB

constexpr int DIM = 128;

__global__ __launch_bounds__(256) void hist_k(const int* __restrict__ br,
                                              int* __restrict__ counts, int E) {
  const int e = blockIdx.x * 256 + threadIdx.x;
  if (e < E) atomicAdd(&counts[br[e]], 1);
}

__global__ __launch_bounds__(1024) void scan_k(int* __restrict__ counts, int N) {
  // in-place exclusive scan of counts[0..N-1]; counts[N] = total
  __shared__ int sums[1024];
  const int tid = threadIdx.x;
  const int chunk = (N + 1023) / 1024;
  const int lo = min(tid * chunk, N);
  const int hi = min(lo + chunk, N);
  int s = 0;
  for (int i = lo; i < hi; ++i) s += counts[i];
  sums[tid] = s;
  __syncthreads();
  for (int off = 1; off < 1024; off <<= 1) {
    int t = (tid >= off) ? sums[tid - off] : 0;
    __syncthreads();
    sums[tid] += t;
    __syncthreads();
  }
  int run = sums[tid] - s;  // exclusive prefix of this chunk
  for (int i = lo; i < hi; ++i) {
    int c = counts[i];
    counts[i] = run;
    run += c;
  }
  if (tid == 1023) counts[N] = run;
}

__global__ __launch_bounds__(256) void fill_k(const int* __restrict__ br,
                                              int* __restrict__ offsets,
                                              int* __restrict__ edge_list, int E) {
  const int e = blockIdx.x * 256 + threadIdx.x;
  if (e < E) {
    const int p = atomicAdd(&offsets[br[e]], 1);
    edge_list[p] = e;
  }
}

__global__ __launch_bounds__(256, 2) void gemm_neighbor_k(
    const float* __restrict__ X, const float* __restrict__ W,
    const float* __restrict__ bn, float* __restrict__ XWn, int Nrows) {
  __shared__ float Ws[DIM * DIM];  // 64 KB: W[k][u]
  const int tid = threadIdx.x;
  for (int i = tid * 4; i < DIM * DIM; i += 1024)
    *(float4*)(Ws + i) = *(const float4*)(W + i);
  __syncthreads();
  const int tx = tid & 31;
  const int ty = tid >> 5;
  const long r0 = (long)blockIdx.x * 64 + (long)ty * 8;
  long rr[8];
#pragma unroll
  for (int r = 0; r < 8; ++r) {
    long t = r0 + r;
    rr[r] = t < Nrows ? t : (long)(Nrows - 1);
  }
  float acc[8][4];
#pragma unroll
  for (int r = 0; r < 8; ++r)
    acc[r][0] = acc[r][1] = acc[r][2] = acc[r][3] = 0.f;

  for (int k = 0; k < DIM; k += 4) {
    float4 w0 = *(const float4*)(Ws + (k + 0) * DIM + tx * 4);
    float4 w1 = *(const float4*)(Ws + (k + 1) * DIM + tx * 4);
    float4 w2 = *(const float4*)(Ws + (k + 2) * DIM + tx * 4);
    float4 w3 = *(const float4*)(Ws + (k + 3) * DIM + tx * 4);
#pragma unroll
    for (int r = 0; r < 8; ++r) {
      float4 xv = *(const float4*)(X + rr[r] * DIM + k);
      acc[r][0] += xv.x * w0.x + xv.y * w1.x + xv.z * w2.x + xv.w * w3.x;
      acc[r][1] += xv.x * w0.y + xv.y * w1.y + xv.z * w2.y + xv.w * w3.y;
      acc[r][2] += xv.x * w0.z + xv.y * w1.z + xv.z * w2.z + xv.w * w3.z;
      acc[r][3] += xv.x * w0.w + xv.y * w1.w + xv.z * w2.w + xv.w * w3.w;
    }
  }
  const float4 bv = *(const float4*)(bn + tx * 4);
#pragma unroll
  for (int r = 0; r < 8; ++r) {
    if (r0 + r < Nrows) {
      float4 o;
      o.x = acc[r][0] + 0.5f * bv.x;  // fold bn/2: (a+bn/2)+(b+bn/2) = a+b+bn
      o.y = acc[r][1] + 0.5f * bv.y;
      o.z = acc[r][2] + 0.5f * bv.z;
      o.w = acc[r][3] + 0.5f * bv.w;
      *(float4*)(XWn + (r0 + r) * DIM + tx * 4) = o;
    }
  }
}

__global__ __launch_bounds__(256, 2) void final_fused_k(
    const float* __restrict__ X, const float* __restrict__ Wl,
    const float* __restrict__ Wf, const float* __restrict__ bias,
    const float* __restrict__ XWn, const int* __restrict__ offsets,
    const int* __restrict__ edge_list, const int* __restrict__ ra,
    const int* __restrict__ rb, float* __restrict__ out, int Nrows) {
  __shared__ float Wls[DIM * 64];
  __shared__ float Wfs[DIM * 64];
  const int tid = threadIdx.x;
  const int uh = blockIdx.y * 64;
  for (int i = tid * 4; i < DIM * 64; i += 1024) {
    const int k = i >> 6, j = i & 63;
    *(float4*)(Wls + i) = *(const float4*)(Wl + k * DIM + uh + j);
    *(float4*)(Wfs + i) = *(const float4*)(Wf + k * DIM + uh + j);
  }
  __syncthreads();
  const int tx = tid & 15;  // 16 unit groups x4 = 64 units
  const int ty = tid >> 4;  // 16 row groups x4 = 64 rows
  const int u = tx * 4;
  const int ug = uh + u;
  const long r0 = (long)blockIdx.x * 64 + (long)ty * 4;

  // ---- gather phase: conv for my 4 rows x 4 units, from CSR ----
  float convv[4][4];
#pragma unroll
  for (int r = 0; r < 4; ++r)
    convv[r][0] = convv[r][1] = convv[r][2] = convv[r][3] = 0.f;
#pragma unroll
  for (int r = 0; r < 4; ++r) {
    const long row = r0 + r;
    if (row >= Nrows) continue;
    const int pb = (row == 0) ? 0 : offsets[row - 1];  // post-fill semantics
    const int pe = offsets[row];
    for (int p = pb; p < pe; ++p) {
      const int e = edge_list[p];
      const long a = ra[e];
      const long bb = rb[e];
      const float4 va = *(const float4*)(XWn + a * DIM + ug);
      const float4 vb = *(const float4*)(XWn + bb * DIM + ug);
      convv[r][0] += fmaxf(va.x + vb.x, 0.f);
      convv[r][1] += fmaxf(va.y + vb.y, 0.f);
      convv[r][2] += fmaxf(va.z + vb.z, 0.f);
      convv[r][3] += fmaxf(va.w + vb.w, 0.f);
    }
  }

  // ---- GEMM phase ----
  long rr[4];
#pragma unroll
  for (int r = 0; r < 4; ++r) {
    long t = r0 + r;
    rr[r] = t < Nrows ? t : (long)(Nrows - 1);
  }
  float accl[4][4], accf[4][4];
#pragma unroll
  for (int r = 0; r < 4; ++r)
#pragma unroll
    for (int j = 0; j < 4; ++j) {
      accl[r][j] = 0.f;
      accf[r][j] = 0.f;
    }

  for (int k = 0; k < DIM; k += 4) {
    float4 l0 = *(const float4*)(Wls + (k + 0) * 64 + u);
    float4 l1 = *(const float4*)(Wls + (k + 1) * 64 + u);
    float4 l2 = *(const float4*)(Wls + (k + 2) * 64 + u);
    float4 l3 = *(const float4*)(Wls + (k + 3) * 64 + u);
    float4 f0 = *(const float4*)(Wfs + (k + 0) * 64 + u);
    float4 f1 = *(const float4*)(Wfs + (k + 1) * 64 + u);
    float4 f2 = *(const float4*)(Wfs + (k + 2) * 64 + u);
    float4 f3 = *(const float4*)(Wfs + (k + 3) * 64 + u);
#pragma unroll
    for (int r = 0; r < 4; ++r) {
      float4 xv = *(const float4*)(X + rr[r] * DIM + k);
      accl[r][0] += xv.x * l0.x + xv.y * l1.x + xv.z * l2.x + xv.w * l3.x;
      accl[r][1] += xv.x * l0.y + xv.y * l1.y + xv.z * l2.y + xv.w * l3.y;
      accl[r][2] += xv.x * l0.z + xv.y * l1.z + xv.z * l2.z + xv.w * l3.z;
      accl[r][3] += xv.x * l0.w + xv.y * l1.w + xv.z * l2.w + xv.w * l3.w;
      accf[r][0] += xv.x * f0.x + xv.y * f1.x + xv.z * f2.x + xv.w * f3.x;
      accf[r][1] += xv.x * f0.y + xv.y * f1.y + xv.z * f2.y + xv.w * f3.y;
      accf[r][2] += xv.x * f0.z + xv.y * f1.z + xv.z * f2.z + xv.w * f3.z;
      accf[r][3] += xv.x * f0.w + xv.y * f1.w + xv.z * f2.w + xv.w * f3.w;
    }
  }
  const float4 bv = *(const float4*)(bias + ug);
#pragma unroll
  for (int r = 0; r < 4; ++r) {
    if (r0 + r < Nrows) {
      float4 o;
      o.x = fmaxf(accl[r][0] + accf[r][0] * convv[r][0] + bv.x, 0.f);
      o.y = fmaxf(accl[r][1] + accf[r][1] * convv[r][1] + bv.y, 0.f);
      o.z = fmaxf(accl[r][2] + accf[r][2] * convv[r][2] + bv.z, 0.f);
      o.w = fmaxf(accl[r][3] + accf[r][3] * convv[r][3] + bv.w, 0.f);
      *(float4*)(out + (r0 + r) * DIM + ug) = o;
    }
  }
}

extern "C" void kernel_launch(void* const* d_in, const int* in_sizes, int n_in,
                              void* d_out, int out_size, void* d_ws, size_t ws_size,
                              hipStream_t stream) {
  const float* X  = (const float*)d_in[0];
  const int* ra   = (const int*)d_in[1];
  const int* rb   = (const int*)d_in[2];
  const int* br   = (const int*)d_in[3];
  const float* Wl = (const float*)d_in[4];
  const float* Wf = (const float*)d_in[5];
  const float* Wn = (const float*)d_in[6];
  const float* b  = (const float*)d_in[7];
  const float* bn = (const float*)d_in[8];
  float* out = (float*)d_out;

  const int N = in_sizes[0] / DIM;  // 200000
  const int E = in_sizes[1];        // 2000000

  float* XWn     = (float*)d_ws;                        // N*128 f32
  int* offsets   = (int*)(XWn + (size_t)N * DIM);       // N+1 i32
  int* edge_list = offsets + (N + 1);                   // E i32

  hipMemsetAsync(offsets, 0, (size_t)(N + 1) * sizeof(int), stream);
  hist_k<<<(E + 255) / 256, 256, 0, stream>>>(br, offsets, E);
  scan_k<<<1, 1024, 0, stream>>>(offsets, N);
  fill_k<<<(E + 255) / 256, 256, 0, stream>>>(br, offsets, edge_list, E);

  const int rowBlocks = (N + 63) / 64;
  gemm_neighbor_k<<<rowBlocks, 256, 0, stream>>>(X, Wn, bn, XWn, N);
  final_fused_k<<<dim3(rowBlocks, 2), 256, 0, stream>>>(
      X, Wl, Wf, b, XWn, offsets, edge_list, ra, rb, out, N);
}

// Round 3
// 919.989 us; speedup vs baseline: 4.3127x; 2.0042x over previous
//
#include <hip/hip_runtime.h>

// WL2 graph-conv layer, MI355X — round 3: dedicated row-per-wave CSR gather,
// bf16 XWn, 3-phase coalesced scan.
// Kernels: memset(counts) -> hist -> blockscan -> spine -> add -> fill(edge_ab)
//          -> gemm_neighbor (XWn bf16 = X@Wn + 0.5*bn) -> gather (conv fp32)
//          -> final fused GEMM+epilogue.
// ws: [XWnb: N*128 bf16 = 51.2MB][conv: N*128 f32 = 102.4MB]
//     [counts N][offsets N][blocksums 1024][edge_ab E*int2 = 16MB]  ~= 171.5 MB

constexpr int DIM = 128;

__device__ __forceinline__ float b2f(unsigned short h) {
  union { float f; unsigned int u; } x;
  x.u = (unsigned int)h << 16;
  return x.f;
}
__device__ __forceinline__ unsigned short f2b(float f) {
  union { float f; unsigned int u; } x;
  x.f = f;
  unsigned int r = (x.u + 0x7FFFu + ((x.u >> 16) & 1u)) >> 16;  // RNE
  return (unsigned short)r;
}

__global__ __launch_bounds__(256) void hist_k(const int* __restrict__ br,
                                              int* __restrict__ counts, int E) {
  const int e = blockIdx.x * 256 + threadIdx.x;
  if (e < E) atomicAdd(&counts[br[e]], 1);
}

__global__ __launch_bounds__(256) void blockscan_k(const int* __restrict__ counts,
                                                   int* __restrict__ offsets,
                                                   int* __restrict__ blocksums, int N) {
  __shared__ int s[256];
  const int tid = threadIdx.x;
  const int i = blockIdx.x * 256 + tid;
  const int val = (i < N) ? counts[i] : 0;
  s[tid] = val;
  __syncthreads();
  for (int off = 1; off < 256; off <<= 1) {
    int t = (tid >= off) ? s[tid - off] : 0;
    __syncthreads();
    s[tid] += t;
    __syncthreads();
  }
  const int incl = s[tid];
  if (i < N) offsets[i] = incl - val;  // block-local exclusive
  if (tid == 255) blocksums[blockIdx.x] = incl;
}

__global__ __launch_bounds__(1024) void spine_k(int* __restrict__ blocksums, int NB) {
  __shared__ int s[1024];
  const int tid = threadIdx.x;
  const int val = (tid < NB) ? blocksums[tid] : 0;
  s[tid] = val;
  __syncthreads();
  for (int off = 1; off < 1024; off <<= 1) {
    int t = (tid >= off) ? s[tid - off] : 0;
    __syncthreads();
    s[tid] += t;
    __syncthreads();
  }
  if (tid < NB) blocksums[tid] = s[tid] - val;  // exclusive
}

__global__ __launch_bounds__(256) void add_k(int* __restrict__ offsets,
                                             const int* __restrict__ blocksums, int N) {
  const int i = blockIdx.x * 256 + threadIdx.x;
  if (i < N) offsets[i] += blocksums[blockIdx.x];
}

__global__ __launch_bounds__(256) void fill_k(const int* __restrict__ ra,
                                              const int* __restrict__ rb,
                                              const int* __restrict__ br,
                                              int* __restrict__ offsets,
                                              int2* __restrict__ edge_ab, int E) {
  const int e = blockIdx.x * 256 + threadIdx.x;
  if (e < E) {
    const int p = atomicAdd(&offsets[br[e]], 1);
    edge_ab[p] = make_int2(ra[e], rb[e]);
  }
}

__global__ __launch_bounds__(256, 2) void gemm_neighbor_k(
    const float* __restrict__ X, const float* __restrict__ W,
    const float* __restrict__ bn, unsigned short* __restrict__ XWnb, int Nrows) {
  __shared__ float Ws[DIM * DIM];  // 64 KB: W[k][u]
  const int tid = threadIdx.x;
  for (int i = tid * 4; i < DIM * DIM; i += 1024)
    *(float4*)(Ws + i) = *(const float4*)(W + i);
  __syncthreads();
  const int tx = tid & 31;
  const int ty = tid >> 5;
  const long r0 = (long)blockIdx.x * 64 + (long)ty * 8;
  long rr[8];
#pragma unroll
  for (int r = 0; r < 8; ++r) {
    long t = r0 + r;
    rr[r] = t < Nrows ? t : (long)(Nrows - 1);
  }
  float acc[8][4];
#pragma unroll
  for (int r = 0; r < 8; ++r)
    acc[r][0] = acc[r][1] = acc[r][2] = acc[r][3] = 0.f;

  for (int k = 0; k < DIM; k += 4) {
    float4 w0 = *(const float4*)(Ws + (k + 0) * DIM + tx * 4);
    float4 w1 = *(const float4*)(Ws + (k + 1) * DIM + tx * 4);
    float4 w2 = *(const float4*)(Ws + (k + 2) * DIM + tx * 4);
    float4 w3 = *(const float4*)(Ws + (k + 3) * DIM + tx * 4);
#pragma unroll
    for (int r = 0; r < 8; ++r) {
      float4 xv = *(const float4*)(X + rr[r] * DIM + k);
      acc[r][0] += xv.x * w0.x + xv.y * w1.x + xv.z * w2.x + xv.w * w3.x;
      acc[r][1] += xv.x * w0.y + xv.y * w1.y + xv.z * w2.y + xv.w * w3.y;
      acc[r][2] += xv.x * w0.z + xv.y * w1.z + xv.z * w2.z + xv.w * w3.z;
      acc[r][3] += xv.x * w0.w + xv.y * w1.w + xv.z * w2.w + xv.w * w3.w;
    }
  }
  const float4 bv = *(const float4*)(bn + tx * 4);
#pragma unroll
  for (int r = 0; r < 8; ++r) {
    if (r0 + r < Nrows) {
      ushort4 o;
      o.x = f2b(acc[r][0] + 0.5f * bv.x);  // fold bn/2: (a+bn/2)+(b+bn/2)=a+b+bn
      o.y = f2b(acc[r][1] + 0.5f * bv.y);
      o.z = f2b(acc[r][2] + 0.5f * bv.z);
      o.w = f2b(acc[r][3] + 0.5f * bv.w);
      *(ushort4*)(XWnb + (r0 + r) * DIM + tx * 4) = o;
    }
  }
}

__global__ __launch_bounds__(256) void gather_k(
    const unsigned short* __restrict__ XWnb, const int* __restrict__ offsets,
    const int2* __restrict__ edge_ab, float* __restrict__ conv, int Nrows) {
  const int wave = threadIdx.x >> 6;
  const long row = (long)blockIdx.x * 4 + wave;
  if (row >= Nrows) return;
  const int lane = threadIdx.x & 63;
  const int slot = lane >> 5;   // half-wave picks alternating edges
  const int sl = lane & 31;     // 32 lanes x 4 units = 128
  const int pb = (row == 0) ? 0 : offsets[row - 1];  // post-fill: offsets[r]=end
  const int pe = offsets[row];
  float4 acc = make_float4(0.f, 0.f, 0.f, 0.f);
  for (int p = pb + slot; p < pe; p += 2) {
    const int2 ab = edge_ab[p];
    const ushort4 ha = *(const ushort4*)(XWnb + (long)ab.x * DIM + sl * 4);
    const ushort4 hb = *(const ushort4*)(XWnb + (long)ab.y * DIM + sl * 4);
    acc.x += fmaxf(b2f(ha.x) + b2f(hb.x), 0.f);
    acc.y += fmaxf(b2f(ha.y) + b2f(hb.y), 0.f);
    acc.z += fmaxf(b2f(ha.z) + b2f(hb.z), 0.f);
    acc.w += fmaxf(b2f(ha.w) + b2f(hb.w), 0.f);
  }
  acc.x += __shfl_xor(acc.x, 32);
  acc.y += __shfl_xor(acc.y, 32);
  acc.z += __shfl_xor(acc.z, 32);
  acc.w += __shfl_xor(acc.w, 32);
  if (slot == 0) *(float4*)(conv + row * DIM + sl * 4) = acc;
}

__global__ __launch_bounds__(256, 2) void final_fused_k(
    const float* __restrict__ X, const float* __restrict__ Wl,
    const float* __restrict__ Wf, const float* __restrict__ bias,
    const float* __restrict__ conv, float* __restrict__ out, int Nrows) {
  __shared__ float Wls[DIM * 64];
  __shared__ float Wfs[DIM * 64];
  const int tid = threadIdx.x;
  const int uh = blockIdx.y * 64;
  for (int i = tid * 4; i < DIM * 64; i += 1024) {
    const int k = i >> 6, j = i & 63;
    *(float4*)(Wls + i) = *(const float4*)(Wl + k * DIM + uh + j);
    *(float4*)(Wfs + i) = *(const float4*)(Wf + k * DIM + uh + j);
  }
  __syncthreads();
  const int tx = tid & 15;
  const int ty = tid >> 4;
  const int u = tx * 4;
  const int ug = uh + u;
  const long r0 = (long)blockIdx.x * 64 + (long)ty * 4;
  long rr[4];
#pragma unroll
  for (int r = 0; r < 4; ++r) {
    long t = r0 + r;
    rr[r] = t < Nrows ? t : (long)(Nrows - 1);
  }
  float accl[4][4], accf[4][4];
#pragma unroll
  for (int r = 0; r < 4; ++r)
#pragma unroll
    for (int j = 0; j < 4; ++j) {
      accl[r][j] = 0.f;
      accf[r][j] = 0.f;
    }

  for (int k = 0; k < DIM; k += 4) {
    float4 l0 = *(const float4*)(Wls + (k + 0) * 64 + u);
    float4 l1 = *(const float4*)(Wls + (k + 1) * 64 + u);
    float4 l2 = *(const float4*)(Wls + (k + 2) * 64 + u);
    float4 l3 = *(const float4*)(Wls + (k + 3) * 64 + u);
    float4 f0 = *(const float4*)(Wfs + (k + 0) * 64 + u);
    float4 f1 = *(const float4*)(Wfs + (k + 1) * 64 + u);
    float4 f2 = *(const float4*)(Wfs + (k + 2) * 64 + u);
    float4 f3 = *(const float4*)(Wfs + (k + 3) * 64 + u);
#pragma unroll
    for (int r = 0; r < 4; ++r) {
      float4 xv = *(const float4*)(X + rr[r] * DIM + k);
      accl[r][0] += xv.x * l0.x + xv.y * l1.x + xv.z * l2.x + xv.w * l3.x;
      accl[r][1] += xv.x * l0.y + xv.y * l1.y + xv.z * l2.y + xv.w * l3.y;
      accl[r][2] += xv.x * l0.z + xv.y * l1.z + xv.z * l2.z + xv.w * l3.z;
      accl[r][3] += xv.x * l0.w + xv.y * l1.w + xv.z * l2.w + xv.w * l3.w;
      accf[r][0] += xv.x * f0.x + xv.y * f1.x + xv.z * f2.x + xv.w * f3.x;
      accf[r][1] += xv.x * f0.y + xv.y * f1.y + xv.z * f2.y + xv.w * f3.y;
      accf[r][2] += xv.x * f0.z + xv.y * f1.z + xv.z * f2.z + xv.w * f3.z;
      accf[r][3] += xv.x * f0.w + xv.y * f1.w + xv.z * f2.w + xv.w * f3.w;
    }
  }
  const float4 bv = *(const float4*)(bias + ug);
#pragma unroll
  for (int r = 0; r < 4; ++r) {
    if (r0 + r < Nrows) {
      const float4 cv = *(const float4*)(conv + (r0 + r) * DIM + ug);
      float4 o;
      o.x = fmaxf(accl[r][0] + accf[r][0] * cv.x + bv.x, 0.f);
      o.y = fmaxf(accl[r][1] + accf[r][1] * cv.y + bv.y, 0.f);
      o.z = fmaxf(accl[r][2] + accf[r][2] * cv.z + bv.z, 0.f);
      o.w = fmaxf(accl[r][3] + accf[r][3] * cv.w + bv.w, 0.f);
      *(float4*)(out + (r0 + r) * DIM + ug) = o;
    }
  }
}

extern "C" void kernel_launch(void* const* d_in, const int* in_sizes, int n_in,
                              void* d_out, int out_size, void* d_ws, size_t ws_size,
                              hipStream_t stream) {
  const float* X  = (const float*)d_in[0];
  const int* ra   = (const int*)d_in[1];
  const int* rb   = (const int*)d_in[2];
  const int* br   = (const int*)d_in[3];
  const float* Wl = (const float*)d_in[4];
  const float* Wf = (const float*)d_in[5];
  const float* Wn = (const float*)d_in[6];
  const float* b  = (const float*)d_in[7];
  const float* bn = (const float*)d_in[8];
  float* out = (float*)d_out;

  const int N = in_sizes[0] / DIM;  // 200000
  const int E = in_sizes[1];        // 2000000

  unsigned short* XWnb = (unsigned short*)d_ws;              // N*128 bf16
  float* conv = (float*)(XWnb + (size_t)N * DIM);            // N*128 f32
  int* counts = (int*)(conv + (size_t)N * DIM);              // N
  int* offsets = counts + N;                                 // N
  int* blocksums = offsets + N;                              // 1024
  int2* edge_ab = (int2*)(blocksums + 1024);                 // E int2

  const int NB = (N + 255) / 256;  // 782 <= 1024

  hipMemsetAsync(counts, 0, (size_t)N * sizeof(int), stream);
  hist_k<<<(E + 255) / 256, 256, 0, stream>>>(br, counts, E);
  blockscan_k<<<NB, 256, 0, stream>>>(counts, offsets, blocksums, N);
  spine_k<<<1, 1024, 0, stream>>>(blocksums, NB);
  add_k<<<NB, 256, 0, stream>>>(offsets, blocksums, N);
  fill_k<<<(E + 255) / 256, 256, 0, stream>>>(ra, rb, br, offsets, edge_ab, E);

  const int rowBlocks = (N + 63) / 64;
  gemm_neighbor_k<<<rowBlocks, 256, 0, stream>>>(X, Wn, bn, XWnb, N);
  gather_k<<<(N + 3) / 4, 256, 0, stream>>>(XWnb, offsets, edge_ab, conv, N);
  final_fused_k<<<dim3(rowBlocks, 2), 256, 0, stream>>>(X, Wl, Wf, b, conv, out, N);
}

// Round 4
// 713.322 us; speedup vs baseline: 5.5622x; 1.2897x over previous
//
#include <hip/hip_runtime.h>

// WL2 graph-conv layer, MI355X — round 4: f16 MFMA GEMMs, fp16 XWn/Xh, quarter-wave gather.
// transpose_w -> memset -> hist -> blockscan -> spine -> add -> fill
//   -> neighbor_mfma (XWnh = f16(X@Wn + bn/2), also emits Xh)
//   -> gather (conv fp32 from CSR, fp16 reads)
//   -> final_mfma (out = relu(Xh@Wl + (Xh@Wf)*conv + b))
// ws: [XWnh 25.6MB][conv 102.4MB][Xh 25.6MB][counts][offsets][blocksums][edge_ab 16MB][WlT/WfT/WnT]

constexpr int DIM = 128;

typedef _Float16 half_t;
typedef __attribute__((ext_vector_type(8))) _Float16 half8;
typedef __attribute__((ext_vector_type(4))) float f32x4;

// ---------------- CSR build ----------------
__global__ __launch_bounds__(256) void hist_k(const int* __restrict__ br,
                                              int* __restrict__ counts, int E) {
  const int e = blockIdx.x * 256 + threadIdx.x;
  if (e < E) atomicAdd(&counts[br[e]], 1);
}

__global__ __launch_bounds__(256) void blockscan_k(const int* __restrict__ counts,
                                                   int* __restrict__ offsets,
                                                   int* __restrict__ blocksums, int N) {
  __shared__ int s[256];
  const int tid = threadIdx.x;
  const int i = blockIdx.x * 256 + tid;
  const int val = (i < N) ? counts[i] : 0;
  s[tid] = val;
  __syncthreads();
  for (int off = 1; off < 256; off <<= 1) {
    int t = (tid >= off) ? s[tid - off] : 0;
    __syncthreads();
    s[tid] += t;
    __syncthreads();
  }
  const int incl = s[tid];
  if (i < N) offsets[i] = incl - val;
  if (tid == 255) blocksums[blockIdx.x] = incl;
}

__global__ __launch_bounds__(1024) void spine_k(int* __restrict__ blocksums, int NB) {
  __shared__ int s[1024];
  const int tid = threadIdx.x;
  const int val = (tid < NB) ? blocksums[tid] : 0;
  s[tid] = val;
  __syncthreads();
  for (int off = 1; off < 1024; off <<= 1) {
    int t = (tid >= off) ? s[tid - off] : 0;
    __syncthreads();
    s[tid] += t;
    __syncthreads();
  }
  if (tid < NB) blocksums[tid] = s[tid] - val;
}

__global__ __launch_bounds__(256) void add_k(int* __restrict__ offsets,
                                             const int* __restrict__ blocksums, int N) {
  const int i = blockIdx.x * 256 + threadIdx.x;
  if (i < N) offsets[i] += blocksums[blockIdx.x];
}

__global__ __launch_bounds__(256) void fill_k(const int* __restrict__ ra,
                                              const int* __restrict__ rb,
                                              const int* __restrict__ br,
                                              int* __restrict__ offsets,
                                              int2* __restrict__ edge_ab, int E) {
  const int e = blockIdx.x * 256 + threadIdx.x;
  if (e < E) {
    const int p = atomicAdd(&offsets[br[e]], 1);
    edge_ab[p] = make_int2(ra[e], rb[e]);
  }
}

// ---------------- W transpose (fp32 [k][u] -> fp16 [u][k]) ----------------
__global__ __launch_bounds__(256) void transpose_w_k(
    const float* __restrict__ Wl, const float* __restrict__ Wf,
    const float* __restrict__ Wn, half_t* __restrict__ WlT,
    half_t* __restrict__ WfT, half_t* __restrict__ WnT) {
  __shared__ float t0[32][33], t1[32][33], t2[32][33];
  const int bx = (blockIdx.x & 3) * 32;   // u-tile
  const int by = (blockIdx.x >> 2) * 32;  // k-tile
  const int x = threadIdx.x & 31;
  const int y4 = (threadIdx.x >> 5) * 4;
#pragma unroll
  for (int i = 0; i < 4; ++i) {
    t0[y4 + i][x] = Wl[(by + y4 + i) * DIM + bx + x];
    t1[y4 + i][x] = Wf[(by + y4 + i) * DIM + bx + x];
    t2[y4 + i][x] = Wn[(by + y4 + i) * DIM + bx + x];
  }
  __syncthreads();
#pragma unroll
  for (int i = 0; i < 4; ++i) {
    WlT[(bx + y4 + i) * DIM + by + x] = (half_t)t0[x][y4 + i];
    WfT[(bx + y4 + i) * DIM + by + x] = (half_t)t1[x][y4 + i];
    WnT[(bx + y4 + i) * DIM + by + x] = (half_t)t2[x][y4 + i];
  }
}

// ---------------- neighbor GEMM (MFMA f16): XWnh = X@Wn + bn/2; emits Xh ----------------
__global__ __launch_bounds__(256) void neighbor_mfma_k(
    const float* __restrict__ X, const half_t* __restrict__ WnT,
    const float* __restrict__ bn, half_t* __restrict__ XWnh,
    half_t* __restrict__ Xh, int Nrows) {
  __shared__ half_t WT[DIM][136];  // W^T [u][k], +8 pad -> 2-way frag reads
  const int tid = threadIdx.x;
  for (int id = tid; id < 2048; id += 256) {
    const int u = id >> 4, c = (id & 15) * 8;
    *(half8*)(&WT[u][c]) = *(const half8*)(WnT + u * DIM + c);
  }
  __syncthreads();
  const int wave = tid >> 6, lane = tid & 63;
  const int ln = lane & 15, quad = lane >> 4;
  const long r0 = (long)blockIdx.x * 128 + wave * 32;
  f32x4 acc[2][8];
#pragma unroll
  for (int mt = 0; mt < 2; ++mt)
#pragma unroll
    for (int n = 0; n < 8; ++n) acc[mt][n] = (f32x4){0.f, 0.f, 0.f, 0.f};

  for (int kt = 0; kt < DIM; kt += 32) {
    half8 afr[2];
#pragma unroll
    for (int mt = 0; mt < 2; ++mt) {
      long row = r0 + mt * 16 + ln;
      if (row >= Nrows) row = Nrows - 1;
      const float* xp = X + row * DIM + kt + quad * 8;
      const float4 x0 = *(const float4*)xp;
      const float4 x1 = *(const float4*)(xp + 4);
      half8 a;
      a[0] = (half_t)x0.x; a[1] = (half_t)x0.y; a[2] = (half_t)x0.z; a[3] = (half_t)x0.w;
      a[4] = (half_t)x1.x; a[5] = (half_t)x1.y; a[6] = (half_t)x1.z; a[7] = (half_t)x1.w;
      afr[mt] = a;
      *(half8*)(Xh + row * DIM + kt + quad * 8) = a;  // fp16 X for final kernel
    }
#pragma unroll
    for (int n = 0; n < 8; ++n) {
      const half8 b = *(const half8*)(&WT[n * 16 + ln][kt + quad * 8]);
      acc[0][n] = __builtin_amdgcn_mfma_f32_16x16x32_f16(afr[0], b, acc[0][n], 0, 0, 0);
      acc[1][n] = __builtin_amdgcn_mfma_f32_16x16x32_f16(afr[1], b, acc[1][n], 0, 0, 0);
    }
  }
  // epilogue: + bn/2 (fold so (a+bn/2)+(b+bn/2)=a+b+bn), store fp16
#pragma unroll
  for (int n = 0; n < 8; ++n) {
    const int col = n * 16 + ln;
    const float bv = 0.5f * bn[col];
#pragma unroll
    for (int mt = 0; mt < 2; ++mt)
#pragma unroll
      for (int r = 0; r < 4; ++r) {
        const long row = r0 + mt * 16 + quad * 4 + r;
        if (row < Nrows) XWnh[row * DIM + col] = (half_t)(acc[mt][n][r] + bv);
      }
  }
}

// ---------------- CSR gather: conv[row] = sum relu(XWn[a]+XWn[b]) ----------------
__global__ __launch_bounds__(256) void gather_k(
    const half_t* __restrict__ XWnh, const int* __restrict__ offsets,
    const int2* __restrict__ edge_ab, float* __restrict__ conv, int Nrows) {
  const int wave = threadIdx.x >> 6;
  const long row = (long)blockIdx.x * 4 + wave;
  if (row >= Nrows) return;
  const int lane = threadIdx.x & 63;
  const int sub = lane >> 4;  // quarter-wave: 4 edges in flight
  const int sl = lane & 15;   // 16 lanes x 8 units
  const int pb = (row == 0) ? 0 : offsets[row - 1];  // post-fill: offsets[r]=end
  const int pe = offsets[row];
  float acc[8] = {0.f, 0.f, 0.f, 0.f, 0.f, 0.f, 0.f, 0.f};
  for (int p = pb + sub; p < pe; p += 4) {
    const int2 ab = edge_ab[p];
    const half8 ha = *(const half8*)(XWnh + (long)ab.x * DIM + sl * 8);
    const half8 hb = *(const half8*)(XWnh + (long)ab.y * DIM + sl * 8);
#pragma unroll
    for (int j = 0; j < 8; ++j)
      acc[j] += fmaxf((float)ha[j] + (float)hb[j], 0.f);
  }
#pragma unroll
  for (int j = 0; j < 8; ++j) {
    acc[j] += __shfl_xor(acc[j], 16);
    acc[j] += __shfl_xor(acc[j], 32);
  }
  if (sub == 0) {
    float4 o0 = make_float4(acc[0], acc[1], acc[2], acc[3]);
    float4 o1 = make_float4(acc[4], acc[5], acc[6], acc[7]);
    *(float4*)(conv + row * DIM + sl * 8) = o0;
    *(float4*)(conv + row * DIM + sl * 8 + 4) = o1;
  }
}

// ---------------- final fused GEMM (MFMA f16) + epilogue ----------------
__global__ __launch_bounds__(256, 2) void final_mfma_k(
    const half_t* __restrict__ Xh, const half_t* __restrict__ WlT,
    const half_t* __restrict__ WfT, const float* __restrict__ bias,
    const float* __restrict__ conv, float* __restrict__ out, int Nrows) {
  __shared__ half_t WTl[DIM][136];
  __shared__ half_t WTf[DIM][136];
  const int tid = threadIdx.x;
  for (int id = tid; id < 2048; id += 256) {
    const int u = id >> 4, c = (id & 15) * 8;
    *(half8*)(&WTl[u][c]) = *(const half8*)(WlT + u * DIM + c);
    *(half8*)(&WTf[u][c]) = *(const half8*)(WfT + u * DIM + c);
  }
  __syncthreads();
  const int wave = tid >> 6, lane = tid & 63;
  const int ln = lane & 15, quad = lane >> 4;
  const long r0 = (long)blockIdx.x * 128 + wave * 32;
  f32x4 accl[2][8], accf[2][8];
#pragma unroll
  for (int mt = 0; mt < 2; ++mt)
#pragma unroll
    for (int n = 0; n < 8; ++n) {
      accl[mt][n] = (f32x4){0.f, 0.f, 0.f, 0.f};
      accf[mt][n] = (f32x4){0.f, 0.f, 0.f, 0.f};
    }

  for (int kt = 0; kt < DIM; kt += 32) {
    half8 afr[2];
#pragma unroll
    for (int mt = 0; mt < 2; ++mt) {
      long row = r0 + mt * 16 + ln;
      if (row >= Nrows) row = Nrows - 1;
      afr[mt] = *(const half8*)(Xh + row * DIM + kt + quad * 8);
    }
#pragma unroll
    for (int n = 0; n < 8; ++n) {
      const half8 bl = *(const half8*)(&WTl[n * 16 + ln][kt + quad * 8]);
      const half8 bf = *(const half8*)(&WTf[n * 16 + ln][kt + quad * 8]);
      accl[0][n] = __builtin_amdgcn_mfma_f32_16x16x32_f16(afr[0], bl, accl[0][n], 0, 0, 0);
      accl[1][n] = __builtin_amdgcn_mfma_f32_16x16x32_f16(afr[1], bl, accl[1][n], 0, 0, 0);
      accf[0][n] = __builtin_amdgcn_mfma_f32_16x16x32_f16(afr[0], bf, accf[0][n], 0, 0, 0);
      accf[1][n] = __builtin_amdgcn_mfma_f32_16x16x32_f16(afr[1], bf, accf[1][n], 0, 0, 0);
    }
  }
#pragma unroll
  for (int n = 0; n < 8; ++n) {
    const int col = n * 16 + ln;
    const float bv = bias[col];
#pragma unroll
    for (int mt = 0; mt < 2; ++mt)
#pragma unroll
      for (int r = 0; r < 4; ++r) {
        const long row = r0 + mt * 16 + quad * 4 + r;
        if (row < Nrows) {
          const float cv = conv[row * DIM + col];
          out[row * DIM + col] = fmaxf(accl[mt][n][r] + accf[mt][n][r] * cv + bv, 0.f);
        }
      }
  }
}

extern "C" void kernel_launch(void* const* d_in, const int* in_sizes, int n_in,
                              void* d_out, int out_size, void* d_ws, size_t ws_size,
                              hipStream_t stream) {
  const float* X  = (const float*)d_in[0];
  const int* ra   = (const int*)d_in[1];
  const int* rb   = (const int*)d_in[2];
  const int* br   = (const int*)d_in[3];
  const float* Wl = (const float*)d_in[4];
  const float* Wf = (const float*)d_in[5];
  const float* Wn = (const float*)d_in[6];
  const float* b  = (const float*)d_in[7];
  const float* bn = (const float*)d_in[8];
  float* out = (float*)d_out;

  const int N = in_sizes[0] / DIM;  // 200000
  const int E = in_sizes[1];        // 2000000

  half_t* XWnh = (half_t*)d_ws;                          // N*128 f16
  float* conv = (float*)(XWnh + (size_t)N * DIM);        // N*128 f32
  half_t* Xh = (half_t*)(conv + (size_t)N * DIM);        // N*128 f16
  int* counts = (int*)(Xh + (size_t)N * DIM);            // N
  int* offsets = counts + N;                             // N
  int* blocksums = offsets + N;                          // 1024
  int2* edge_ab = (int2*)(blocksums + 1024);             // E
  half_t* WlT = (half_t*)(edge_ab + E);                  // 128*128 f16
  half_t* WfT = WlT + DIM * DIM;
  half_t* WnT = WfT + DIM * DIM;

  const int NB = (N + 255) / 256;  // 782 <= 1024

  transpose_w_k<<<16, 256, 0, stream>>>(Wl, Wf, Wn, WlT, WfT, WnT);
  hipMemsetAsync(counts, 0, (size_t)N * sizeof(int), stream);
  hist_k<<<(E + 255) / 256, 256, 0, stream>>>(br, counts, E);
  blockscan_k<<<NB, 256, 0, stream>>>(counts, offsets, blocksums, N);
  spine_k<<<1, 1024, 0, stream>>>(blocksums, NB);
  add_k<<<NB, 256, 0, stream>>>(offsets, blocksums, N);
  fill_k<<<(E + 255) / 256, 256, 0, stream>>>(ra, rb, br, offsets, edge_ab, E);

  const int rowBlocks128 = (N + 127) / 128;
  neighbor_mfma_k<<<rowBlocks128, 256, 0, stream>>>(X, WnT, bn, XWnh, Xh, N);
  gather_k<<<(N + 3) / 4, 256, 0, stream>>>(XWnh, offsets, edge_ab, conv, N);
  final_mfma_k<<<rowBlocks128, 256, 0, stream>>>(Xh, WlT, WfT, b, conv, out, N);
}